// Round 2
// baseline (638.333 us; speedup 1.0000x reference)
//
#include <hip/hip_runtime.h>

// FlyHash-style sparse projection + per-row exact top-k threshold.
//
// Round 14: revert to the proven R12 shape (TPB=1024, FPT=10,
// __launch_bounds__(1024,4)) — R13's 512-thread co-residency experiment was
// neutral (stores already drain past s_endpgm, overlapping the next block's
// phase 1, so there was no serialization to recover).
// Replace the histogram threshold machinery with a candidate list:
//   phase 1: one cmp per value; values >= 4.5 (expected ~157/row, P(<32)
//            astronomically small) push into a per-row 256-entry LDS list.
//   phase 2: one wave per row, register-only select on the list: 64-bin
//            count via broadcast reads (bin == lane), shfl suffix scan to
//            the bracket bin, capture <=64 bracket members into per-lane
//            regs, exact cgt/cge rank select. No atomics, no LDS writes.
//   anomalies (n<k, n>CAP, m2>64) -> existing exact binary-search fallback.
// Deleted: 16KB hist + clearing, per-value bin math + LDS atomics (12% hit
// rate), phase 3a full x4 re-scan, phase 3b, 2 barriers.
// Bit-exactness (absmax 0, R2-R13): serial f32 fold-left ascending ==
// ref einsum accumulation; threshold = an actual x value's bit pattern
// selected by exact rank (ties handled by cgt<j<=cge).

typedef float f4 __attribute__((ext_vector_type(4)));

constexpr int IN_F   = 512;
constexpr int OUT_F  = 10240;
constexpr int TPB    = 1024;
constexpr int ROWS   = 4;                 // batch rows per block
constexpr int FPT    = OUT_F / TPB;       // 10 features per thread
constexpr int NWAVES = TPB / 64;          // 16
constexpr int CAP    = 256;               // candidate list capacity per row
constexpr float CUT  = 4.5f;              // candidate cutoff

// ---------------------------------------------------------------------------
// Kernel 1: extract sparse indices from dense W. One wave per W row.
// Emits indices ASCENDING (required for bit-exact fold-left downstream).
// ---------------------------------------------------------------------------
__global__ __launch_bounds__(256) void extract_idx(const float* __restrict__ W,
                                                   uint4* __restrict__ packed,
                                                   int out_f) {
  int row  = blockIdx.x * 4 + (threadIdx.x >> 6);
  int lane = threadIdx.x & 63;
  if (row >= out_f) return;

  const float* wr = W + (size_t)row * IN_F;
  unsigned long long masks[8];
#pragma unroll
  for (int c = 0; c < 8; ++c) {
    float v = wr[c * 64 + lane];
    masks[c] = __ballot(v != 0.0f);   // entries are exactly 0.0 or 1.0
  }
  if (lane == 0) {
    unsigned idx[6] = {IN_F, IN_F, IN_F, IN_F, IN_F, IN_F};  // pad -> zero slot
    int n = 0;
#pragma unroll
    for (int c = 0; c < 8; ++c) {
      unsigned long long m = masks[c];
      while (m && n < 6) {
        int b = __builtin_ctzll(m);
        idx[n++] = (unsigned)(c * 64 + b);
        m &= m - 1;
      }
    }
    uint4 r;
    r.x = idx[0] | (idx[1] << 16);
    r.y = idx[2] | (idx[3] << 16);
    r.z = idx[4] | (idx[5] << 16);
    r.w = (unsigned)n;
    packed[row] = r;
  }
}

// Serial fold of one row-component r (bit-identical to phase-1's fold).
__device__ __forceinline__ float row_val(const f4* in4, uint4 p, int r) {
  const float* b = (const float*)in4;
  float s = b[(p.x & 0xFFFFu) * 4 + r];
  s += b[(p.x >> 16) * 4 + r];
  s += b[(p.y & 0xFFFFu) * 4 + r];
  s += b[(p.y >> 16) * 4 + r];
  s += b[(p.z & 0xFFFFu) * 4 + r];
  s += b[(p.z >> 16) * 4 + r];
  return s;
}

// ---------------------------------------------------------------------------
// Kernel 2: 4 batch rows per block, 1024 threads, x4[10] persisted (40 VGPR).
// ---------------------------------------------------------------------------
__global__ __launch_bounds__(TPB, 4) void fly_hash(const float* __restrict__ inp,
                                                   const uint4* __restrict__ packed,
                                                   const int* __restrict__ kptr,
                                                   float* __restrict__ out) {
  __shared__ f4    in4[IN_F + 1];       // 8.2 KB; [IN_F] = zero slot for pads
  __shared__ int   wsum[NWAVES];
  __shared__ int   sh_cnt[ROWS];
  __shared__ float sh_list[ROWS][CAP];  // 4 KB candidate lists
  __shared__ float sh_thr[ROWS];
  __shared__ int   sh_need[ROWS];       // 1 -> fallback binary search

  const int tid  = threadIdx.x;
  const int lane = tid & 63;
  const int wid  = tid >> 6;
  const int row0 = blockIdx.x * ROWS;
  const int k    = *kptr;               // hash_length (32)

  // --- stage 4 input rows transposed into LDS ---------------------------
  if (tid < IN_F) {
    const float* p = inp + (size_t)row0 * IN_F + tid;
    f4 v;
    v.x = p[0];
    v.y = p[IN_F];
    v.z = p[2 * IN_F];
    v.w = p[3 * IN_F];
    in4[tid] = v;                       // ds_write_b128, conflict-free
  } else if (tid == IN_F) {
    f4 z = {0.0f, 0.0f, 0.0f, 0.0f};
    in4[IN_F] = z;
  }
  if (tid < ROWS) sh_cnt[tid] = 0;
  __syncthreads();

  // --- phase 1: compute x (bit-exact serial fold-left) + candidate push --
  f4 x4[FPT];
#pragma unroll
  for (int i = 0; i < FPT; ++i) {
    uint4 r = packed[tid + i * TPB];
    f4 s = in4[r.x & 0xFFFFu];          // ds_read_b128: 4 rows per gather
    s += in4[r.x >> 16];
    s += in4[r.y & 0xFFFFu];
    s += in4[r.y >> 16];
    s += in4[r.z & 0xFFFFu];
    s += in4[r.z >> 16];
    x4[i] = s;
#pragma unroll
    for (int rr = 0; rr < ROWS; ++rr) {
      float v = s[rr];
      if (v >= CUT) {                   // ~1.6% of values
        int p = atomicAdd(&sh_cnt[rr], 1);
        if (p < CAP) sh_list[rr][p] = v;
      }
    }
  }
  __syncthreads();

  // --- phase 2: wave r rank-selects the k-th largest of row r's list -----
  // Register-only: 64-bin counts via broadcast reads (bin == lane), shfl
  // suffix scan, bracket members captured into per-lane regs, exact select.
  if (wid < ROWS) {
    const int r = wid;
    const int n = sh_cnt[r];
    int need = 1;
    if (n >= k && n <= CAP) {
      // pass 1: per-lane bin counts (lane L owns bin L; width 1/32 on [4.5,6.5))
      int cnt = 0;
      for (int m = 0; m < n; ++m) {
        float u = sh_list[r][m];        // broadcast LDS read
        int b = (int)((u - CUT) * 32.0f);
        b = b > 63 ? 63 : b;
        cnt += (b == lane);
      }
      int s = cnt;                      // inclusive suffix sum across lanes
#pragma unroll
      for (int off = 1; off < 64; off <<= 1) {
        int t = __shfl_down(s, off);
        if (lane + off < 64) s += t;
      }
      int s_next = __shfl_down(s, 1);   // suffix starting at lane+1
      if (lane == 63) s_next = 0;
      bool cross = (s >= k) && (s_next < k);   // unique since n >= k
      unsigned long long cm = __ballot(cross);
      int cl = (int)__builtin_ctzll(cm);
      int bsel  = cl;                   // bracket bin == crossing lane index
      int above = __shfl(s_next, cl);   // count in strictly higher bins
      // pass 2: lane i captures the i-th bracket member (list order)
      float vl = -1.0f;
      int m2 = 0;
      for (int m = 0; m < n; ++m) {
        float u = sh_list[r][m];        // broadcast LDS read
        int b = (int)((u - CUT) * 32.0f);
        b = b > 63 ? 63 : b;
        if (b == bsel) {
          if (lane == m2) vl = u;
          ++m2;
        }
      }
      if (m2 <= 64) {
        const int j = k - above;        // 1 <= j <= m2
        int cgt = 0, cge = 0;
        for (int i = 0; i < m2; ++i) {
          float u = __shfl(vl, i);
          cgt += (u > vl);
          cge += (u >= vl);
        }
        if (lane < m2 && cgt < j && cge >= j) sh_thr[r] = vl;  // exact k-th bits
        need = 0;
      }
    }
    if (lane == 0) sh_need[r] = need;
  }
  __syncthreads();

  // --- phase 3: fallback (recomputes from LDS, never touches x4; rare) ---
#pragma unroll 1
  for (int r = 0; r < ROWS; ++r) {
    if (!sh_need[r]) continue;
    unsigned lo = 0u, hi = __float_as_uint(8.0f);
    while (lo < hi) {
      unsigned mid = lo + ((hi - lo + 1u) >> 1);
      float fm = __uint_as_float(mid);
      int c = 0;
      for (int i = 0; i < FPT; ++i) {
        uint4 p = packed[tid + i * TPB];
        c += (int)__popcll(__ballot(row_val(in4, p, r) >= fm));
      }
      if (lane == 0) wsum[wid] = c;
      __syncthreads();
      int tot = 0;
#pragma unroll
      for (int w = 0; w < NWAVES; ++w) tot += wsum[w];
      if (tot >= k) lo = mid; else hi = mid - 1u;
      __syncthreads();
    }
    if (tid == 0) sh_thr[r] = __uint_as_float(lo);
    __syncthreads();
  }
  const float t0 = sh_thr[0];
  const float t1 = sh_thr[1];
  const float t2 = sh_thr[2];
  const float t3 = sh_thr[3];

  // --- phase 4: thresholded writes, 4 coalesced nontemporal streams ------
  float* o0 = out + (size_t)(row0 + 0) * OUT_F;
  float* o1 = out + (size_t)(row0 + 1) * OUT_F;
  float* o2 = out + (size_t)(row0 + 2) * OUT_F;
  float* o3 = out + (size_t)(row0 + 3) * OUT_F;
#pragma unroll
  for (int i = 0; i < FPT; ++i) {
    int f = tid + i * TPB;
    f4 v = x4[i];
    __builtin_nontemporal_store((v.x >= t0) ? v.x : 0.0f, &o0[f]);
    __builtin_nontemporal_store((v.y >= t1) ? v.y : 0.0f, &o1[f]);
    __builtin_nontemporal_store((v.z >= t2) ? v.z : 0.0f, &o2[f]);
    __builtin_nontemporal_store((v.w >= t3) ? v.w : 0.0f, &o3[f]);
  }
}

// ---------------------------------------------------------------------------
extern "C" void kernel_launch(void* const* d_in, const int* in_sizes, int n_in,
                              void* d_out, int out_size, void* d_ws, size_t ws_size,
                              hipStream_t stream) {
  const float* inp = (const float*)d_in[0];
  const float* W   = (const float*)d_in[1];
  const int* kptr  = (const int*)d_in[2];
  float* out       = (float*)d_out;

  const int batch = in_sizes[0] / IN_F;   // 4096
  const int out_f = in_sizes[1] / IN_F;   // 10240

  uint4* packed = (uint4*)d_ws;           // 10240 * 16 B = 160 KB scratch

  hipLaunchKernelGGL(extract_idx, dim3((out_f + 3) / 4), dim3(256), 0, stream,
                     W, packed, out_f);
  hipLaunchKernelGGL(fly_hash, dim3(batch / ROWS), dim3(TPB), 0, stream,
                     inp, packed, kptr, out);
}

// Round 4
// 312.841 us; speedup vs baseline: 2.0404x; 2.0404x over previous
//
#include <hip/hip_runtime.h>

// FlyHash-style sparse projection + per-row exact top-k threshold.
//
// Round 16 = R15 resubmitted verbatim (previous bench died on container
// acquire, not on the kernel). R15 = exact R12 champion (TPB=1024, ROWS=4,
// FPT=10, 1024-bin histogram + wave-parallel bracket scan + list select +
// fallback, __launch_bounds__(1024,4)) with ONE structural change: grid 512
// instead of 1024, each block processes 2 chunks (blockIdx.x and
// blockIdx.x+512) back-to-back. Stores read registers at issue, so chunk
// 1's nontemporal store drain (~27us of HBM) overlaps chunk 2's
// LDS-gather/fold phase deterministically, instead of relying on lucky
// cross-block scheduling. 512 blocks = 2 co-resident per CU.
// R13 (512-thr co-residency) and R14 (candidate-list select) both
// regressed and are abandoned; lesson from R14: dynamic-bound serial LDS
// loops and same-address LDS atomics are poison (4.4e7 bank-conflict
// cycles). The scattered 1024-bin histogram is cheap and stays.
// Bit-exactness (absmax 0, R2-R14): serial f32 fold-left ascending ==
// ref einsum accumulation; threshold = an actual x value's bit pattern.

typedef float f4 __attribute__((ext_vector_type(4)));

constexpr int IN_F   = 512;
constexpr int OUT_F  = 10240;
constexpr int TPB    = 1024;
constexpr int ROWS   = 4;                 // batch rows per chunk
constexpr int CHUNKS = 2;                 // chunks per block
constexpr int FPT    = OUT_F / TPB;       // 10 features per thread
constexpr int NBINS  = 1024;              // per-row bins over [4,6), width 1/512
constexpr int NWAVES = TPB / 64;          // 16
constexpr int CAP    = 64;                // bracket-bin list capacity per row

static_assert(NBINS == 64 * 16, "wave scan assumes 16 bins per lane");

// ---------------------------------------------------------------------------
// Kernel 1: extract sparse indices from dense W. One wave per W row.
// Emits indices ASCENDING (required for bit-exact fold-left downstream).
// ---------------------------------------------------------------------------
__global__ __launch_bounds__(256) void extract_idx(const float* __restrict__ W,
                                                   uint4* __restrict__ packed,
                                                   int out_f) {
  int row  = blockIdx.x * 4 + (threadIdx.x >> 6);
  int lane = threadIdx.x & 63;
  if (row >= out_f) return;

  const float* wr = W + (size_t)row * IN_F;
  unsigned long long masks[8];
#pragma unroll
  for (int c = 0; c < 8; ++c) {
    float v = wr[c * 64 + lane];
    masks[c] = __ballot(v != 0.0f);   // entries are exactly 0.0 or 1.0
  }
  if (lane == 0) {
    unsigned idx[6] = {IN_F, IN_F, IN_F, IN_F, IN_F, IN_F};  // pad -> zero slot
    int n = 0;
#pragma unroll
    for (int c = 0; c < 8; ++c) {
      unsigned long long m = masks[c];
      while (m && n < 6) {
        int b = __builtin_ctzll(m);
        idx[n++] = (unsigned)(c * 64 + b);
        m &= m - 1;
      }
    }
    uint4 r;
    r.x = idx[0] | (idx[1] << 16);
    r.y = idx[2] | (idx[3] << 16);
    r.z = idx[4] | (idx[5] << 16);
    r.w = (unsigned)n;
    packed[row] = r;
  }
}

// Serial fold of one row-component r (bit-identical to phase-1's fold).
__device__ __forceinline__ float row_val(const f4* in4, uint4 p, int r) {
  const float* b = (const float*)in4;
  float s = b[(p.x & 0xFFFFu) * 4 + r];
  s += b[(p.x >> 16) * 4 + r];
  s += b[(p.y & 0xFFFFu) * 4 + r];
  s += b[(p.y >> 16) * 4 + r];
  s += b[(p.z & 0xFFFFu) * 4 + r];
  s += b[(p.z >> 16) * 4 + r];
  return s;
}

// ---------------------------------------------------------------------------
// Kernel 2: 4 batch rows per chunk, 2 chunks per block, 1024 threads.
// x4[10] persisted per chunk (40 VGPR); chunk 1 store drain overlaps
// chunk 2 gather/fold.
// ---------------------------------------------------------------------------
__global__ __launch_bounds__(TPB, 4) void fly_hash(const float* __restrict__ inp,
                                                   const uint4* __restrict__ packed,
                                                   const int* __restrict__ kptr,
                                                   float* __restrict__ out,
                                                   int grid) {
  __shared__ f4    in4[IN_F + 1];       // 8.2 KB; [IN_F] = zero slot for pads
  __shared__ int   hist[ROWS * NBINS];  // 16 KB
  __shared__ int   wsum[NWAVES];
  __shared__ int   sh_bstar[ROWS], sh_above[ROWS], sh_n[ROWS], sh_cnt[ROWS];
  __shared__ float sh_list[ROWS][CAP];
  __shared__ float sh_thr[ROWS];
  __shared__ int   sh_need[ROWS];       // 1 -> fallback binary search

  const int tid  = threadIdx.x;
  const int lane = tid & 63;
  const int wid  = tid >> 6;
  const int k    = *kptr;               // hash_length (32)

#pragma unroll 1
  for (int chunk = 0; chunk < CHUNKS; ++chunk) {
    const int row0 = (blockIdx.x + chunk * grid) * ROWS;

    // Protect LDS reuse: all threads must be past chunk-1's phase-5
    // t0..t3 register reads and gathers before re-staging.
    if (chunk) __syncthreads();

    // --- stage 4 input rows transposed into LDS -------------------------
    if (tid < IN_F) {
      const float* p = inp + (size_t)row0 * IN_F + tid;
      f4 v;
      v.x = p[0];
      v.y = p[IN_F];
      v.z = p[2 * IN_F];
      v.w = p[3 * IN_F];
      in4[tid] = v;                     // ds_write_b128, conflict-free
    } else if (tid == IN_F) {
      f4 z = {0.0f, 0.0f, 0.0f, 0.0f};
      in4[IN_F] = z;
    }
    if (tid < ROWS) { sh_bstar[tid] = -1; sh_cnt[tid] = 0; }
    for (int i = tid; i < ROWS * NBINS; i += TPB) hist[i] = 0;
    __syncthreads();

    // --- phase 1: compute x (bit-exact serial fold-left) + histogram -----
    f4 x4[FPT];
#pragma unroll
    for (int i = 0; i < FPT; ++i) {
      uint4 r = packed[tid + i * TPB];
      f4 s = in4[r.x & 0xFFFFu];        // ds_read_b128: 4 rows per gather
      s += in4[r.x >> 16];
      s += in4[r.y & 0xFFFFu];
      s += in4[r.y >> 16];
      s += in4[r.z & 0xFFFFu];
      s += in4[r.z >> 16];
      x4[i] = s;
#pragma unroll
      for (int rr = 0; rr < ROWS; ++rr) {
        float v = s[rr];
        if (v >= 4.0f) {                // top-32 of 10240 ~ 4.8; bin >=4 only
          int b = (int)((v - 4.0f) * 512.0f);  // EXACT key (Sterbenz + pow2)
          b = b > NBINS - 1 ? NBINS - 1 : b;
          atomicAdd(&hist[rr * NBINS + b], 1);
        }
      }
    }
    __syncthreads();

    // --- phase 2: wave-parallel bracket-bin search (wave r owns row r) ---
    // Lane L sums bins [16L, 16L+16); 6-step shfl suffix scan; crossing
    // lane walks its 16 bins descending to the exact bin. No barriers.
    if (wid < ROWS) {
      const int r = wid;
      const int base = r * NBINS + lane * 16;
      int csum = 0;
#pragma unroll
      for (int j = 0; j < 16; ++j) csum += hist[base + j];
      int s = csum;                     // inclusive suffix sum across lanes
#pragma unroll
      for (int off = 1; off < 64; off <<= 1) {
        int t = __shfl_down(s, off);
        if (lane + off < 64) s += t;
      }
      int s_next = __shfl_down(s, 1);   // suffix starting at lane+1
      if (lane == 63) s_next = 0;
      if (s >= k && s_next < k) {       // unique crossing chunk (if any)
        int acc = s_next;
        int bsel = lane * 16, abv = s_next;
        for (int b = lane * 16 + 15; b >= lane * 16; --b) {
          int h = hist[r * NBINS + b];
          if (acc + h >= k) { bsel = b; abv = acc; break; }
          acc += h;
        }
        sh_bstar[r] = bsel;
        sh_above[r] = abv;
        sh_n[r]     = hist[r * NBINS + bsel];
      }
    }
    __syncthreads();

    // --- phase 3a: collect bracket-bin members into per-row lists --------
    {
      const int b0 = sh_bstar[0], b1 = sh_bstar[1];
      const int b2 = sh_bstar[2], b3 = sh_bstar[3];
#pragma unroll
      for (int i = 0; i < FPT; ++i) {
        f4 s = x4[i];
#pragma unroll
        for (int rr = 0; rr < ROWS; ++rr) {
          float v = s[rr];
          int bb = (rr == 0) ? b0 : (rr == 1) ? b1 : (rr == 2) ? b2 : b3;
          if (v >= 4.0f) {
            int b = (int)((v - 4.0f) * 512.0f);
            b = b > NBINS - 1 ? NBINS - 1 : b;
            if (b == bb) {
              int p = atomicAdd(&sh_cnt[rr], 1);
              if (p < CAP) sh_list[rr][p] = v;
            }
          }
        }
      }
    }
    __syncthreads();

    // --- phase 3b: wave r rank-selects the (k-above)-th largest ----------
    if (wid < ROWS) {
      const int r   = wid;
      const int bst = sh_bstar[r];
      const int n   = (bst >= 0) ? sh_n[r] : CAP + 1;
      if (bst >= 0 && n <= CAP && sh_cnt[r] <= CAP) {
        const int j = k - sh_above[r];          // 1 <= j <= n
        float vl = (lane < n) ? sh_list[r][lane] : -1.0f;
        int cgt = 0, cge = 0;
        for (int m = 0; m < n; ++m) {
          float u = sh_list[r][m];              // broadcast LDS read
          cgt += (u > vl);
          cge += (u >= vl);
        }
        if (lane < n && cgt < j && cge >= j) sh_thr[r] = vl;  // exact k-th bits
        if (lane == 0) sh_need[r] = 0;
      } else {
        if (lane == 0) sh_need[r] = 1;          // overflow / no bracket
      }
    }
    __syncthreads();

    // --- phase 4: fallback (recomputes from LDS, never touches x4; rare) -
#pragma unroll 1
    for (int r = 0; r < ROWS; ++r) {
      if (!sh_need[r]) continue;
      unsigned lo = 0u, hi = __float_as_uint(8.0f);
      while (lo < hi) {
        unsigned mid = lo + ((hi - lo + 1u) >> 1);
        float fm = __uint_as_float(mid);
        int c = 0;
        for (int i = 0; i < FPT; ++i) {
          uint4 p = packed[tid + i * TPB];
          c += (int)__popcll(__ballot(row_val(in4, p, r) >= fm));
        }
        if (lane == 0) wsum[wid] = c;
        __syncthreads();
        int tot = 0;
#pragma unroll
        for (int w = 0; w < NWAVES; ++w) tot += wsum[w];
        if (tot >= k) lo = mid; else hi = mid - 1u;
        __syncthreads();
      }
      if (tid == 0) sh_thr[r] = __uint_as_float(lo);
      __syncthreads();
    }
    const float t0 = sh_thr[0];
    const float t1 = sh_thr[1];
    const float t2 = sh_thr[2];
    const float t3 = sh_thr[3];

    // --- phase 5: thresholded writes, 4 coalesced nontemporal streams ----
    // Stores read registers at issue; the drain overlaps the next chunk's
    // staging + gather phase (no barrier here).
    float* o0 = out + (size_t)(row0 + 0) * OUT_F;
    float* o1 = out + (size_t)(row0 + 1) * OUT_F;
    float* o2 = out + (size_t)(row0 + 2) * OUT_F;
    float* o3 = out + (size_t)(row0 + 3) * OUT_F;
#pragma unroll
    for (int i = 0; i < FPT; ++i) {
      int f = tid + i * TPB;
      f4 v = x4[i];
      __builtin_nontemporal_store((v.x >= t0) ? v.x : 0.0f, &o0[f]);
      __builtin_nontemporal_store((v.y >= t1) ? v.y : 0.0f, &o1[f]);
      __builtin_nontemporal_store((v.z >= t2) ? v.z : 0.0f, &o2[f]);
      __builtin_nontemporal_store((v.w >= t3) ? v.w : 0.0f, &o3[f]);
    }
  }
}

// ---------------------------------------------------------------------------
extern "C" void kernel_launch(void* const* d_in, const int* in_sizes, int n_in,
                              void* d_out, int out_size, void* d_ws, size_t ws_size,
                              hipStream_t stream) {
  const float* inp = (const float*)d_in[0];
  const float* W   = (const float*)d_in[1];
  const int* kptr  = (const int*)d_in[2];
  float* out       = (float*)d_out;

  const int batch = in_sizes[0] / IN_F;   // 4096
  const int out_f = in_sizes[1] / IN_F;   // 10240

  uint4* packed = (uint4*)d_ws;           // 10240 * 16 B = 160 KB scratch

  const int grid = batch / ROWS / CHUNKS; // 512

  hipLaunchKernelGGL(extract_idx, dim3((out_f + 3) / 4), dim3(256), 0, stream,
                     W, packed, out_f);
  hipLaunchKernelGGL(fly_hash, dim3(grid), dim3(TPB), 0, stream,
                     inp, packed, kptr, out, grid);
}

// Round 5
// 237.107 us; speedup vs baseline: 2.6922x; 1.3194x over previous
//
#include <hip/hip_runtime.h>

// FlyHash-style sparse projection + per-row exact top-k threshold.
//
// Round 17 = exact R12 champion (TPB=1024, grid=1024, ROWS=4, FPT=10,
// 1024-bin histogram + wave-parallel bracket scan + list select + fallback,
// __launch_bounds__(1024,4), nontemporal stores) with ONE change: phase 1
// prefetches all 10 packed uint4s into registers BEFORE the gather/fold
// loop. At VGPR=44 the old code couldn't keep 10 global loads in flight ->
// up to 10 serialized L2 round-trips per thread on the critical path.
// Explicit rk[FPT] gives the scheduler the ILP (one vmcnt exposure);
// ~+40 VGPR stays under the 128 cap at (1024,4), occupancy unchanged.
// Chunking (R15/16) is dead: compiler emits vmcnt(0) before the chunk-top
// s_barrier, putting the store drain ON the critical path (s_endpgm lets
// stores drain under the next block's compute for free), plus spill traffic
// (VGPR 64, +250 MB scratch). R13 (512,4) was neutral because 2x8 waves ==
// 1x16 waves -- no parallelism added.
// Bit-exactness (absmax 0, R2-R16): serial f32 fold-left ascending ==
// ref einsum accumulation; threshold = an actual x value's bit pattern.
// Only load *scheduling* changes here, not values or fold order.

typedef float f4 __attribute__((ext_vector_type(4)));

constexpr int IN_F   = 512;
constexpr int OUT_F  = 10240;
constexpr int TPB    = 1024;
constexpr int ROWS   = 4;                 // batch rows per block
constexpr int FPT    = OUT_F / TPB;       // 10 features per thread
constexpr int NBINS  = 1024;              // per-row bins over [4,6), width 1/512
constexpr int NWAVES = TPB / 64;          // 16
constexpr int CAP    = 64;                // bracket-bin list capacity per row

static_assert(NBINS == 64 * 16, "wave scan assumes 16 bins per lane");

// ---------------------------------------------------------------------------
// Kernel 1: extract sparse indices from dense W. One wave per W row.
// Emits indices ASCENDING (required for bit-exact fold-left downstream).
// ---------------------------------------------------------------------------
__global__ __launch_bounds__(256) void extract_idx(const float* __restrict__ W,
                                                   uint4* __restrict__ packed,
                                                   int out_f) {
  int row  = blockIdx.x * 4 + (threadIdx.x >> 6);
  int lane = threadIdx.x & 63;
  if (row >= out_f) return;

  const float* wr = W + (size_t)row * IN_F;
  unsigned long long masks[8];
#pragma unroll
  for (int c = 0; c < 8; ++c) {
    float v = wr[c * 64 + lane];
    masks[c] = __ballot(v != 0.0f);   // entries are exactly 0.0 or 1.0
  }
  if (lane == 0) {
    unsigned idx[6] = {IN_F, IN_F, IN_F, IN_F, IN_F, IN_F};  // pad -> zero slot
    int n = 0;
#pragma unroll
    for (int c = 0; c < 8; ++c) {
      unsigned long long m = masks[c];
      while (m && n < 6) {
        int b = __builtin_ctzll(m);
        idx[n++] = (unsigned)(c * 64 + b);
        m &= m - 1;
      }
    }
    uint4 r;
    r.x = idx[0] | (idx[1] << 16);
    r.y = idx[2] | (idx[3] << 16);
    r.z = idx[4] | (idx[5] << 16);
    r.w = (unsigned)n;
    packed[row] = r;
  }
}

// Serial fold of one row-component r (bit-identical to phase-1's fold).
__device__ __forceinline__ float row_val(const f4* in4, uint4 p, int r) {
  const float* b = (const float*)in4;
  float s = b[(p.x & 0xFFFFu) * 4 + r];
  s += b[(p.x >> 16) * 4 + r];
  s += b[(p.y & 0xFFFFu) * 4 + r];
  s += b[(p.y >> 16) * 4 + r];
  s += b[(p.z & 0xFFFFu) * 4 + r];
  s += b[(p.z >> 16) * 4 + r];
  return s;
}

// ---------------------------------------------------------------------------
// Kernel 2: 4 batch rows per block, 1024 threads, x4[10] persisted (40 VGPR)
// + rk[10] prefetch (40 VGPR, dies as x4 is born).
// ---------------------------------------------------------------------------
__global__ __launch_bounds__(TPB, 4) void fly_hash(const float* __restrict__ inp,
                                                   const uint4* __restrict__ packed,
                                                   const int* __restrict__ kptr,
                                                   float* __restrict__ out) {
  __shared__ f4    in4[IN_F + 1];       // 8.2 KB; [IN_F] = zero slot for pads
  __shared__ int   hist[ROWS * NBINS];  // 16 KB
  __shared__ int   wsum[NWAVES];
  __shared__ int   sh_bstar[ROWS], sh_above[ROWS], sh_n[ROWS], sh_cnt[ROWS];
  __shared__ float sh_list[ROWS][CAP];
  __shared__ float sh_thr[ROWS];
  __shared__ int   sh_need[ROWS];       // 1 -> fallback binary search

  const int tid  = threadIdx.x;
  const int lane = tid & 63;
  const int wid  = tid >> 6;
  const int row0 = blockIdx.x * ROWS;
  const int k    = *kptr;               // hash_length (32)

  // --- stage 4 input rows transposed into LDS ---------------------------
  if (tid < IN_F) {
    const float* p = inp + (size_t)row0 * IN_F + tid;
    f4 v;
    v.x = p[0];
    v.y = p[IN_F];
    v.z = p[2 * IN_F];
    v.w = p[3 * IN_F];
    in4[tid] = v;                       // ds_write_b128, conflict-free
  } else if (tid == IN_F) {
    f4 z = {0.0f, 0.0f, 0.0f, 0.0f};
    in4[IN_F] = z;
  }
  if (tid < ROWS) { sh_bstar[tid] = -1; sh_cnt[tid] = 0; }
  for (int i = tid; i < ROWS * NBINS; i += TPB) hist[i] = 0;
  __syncthreads();

  // --- phase 1: prefetch ALL packed entries, then gather/fold/bin --------
  // All 10 global loads issue back-to-back (independent addresses): one
  // L2 latency exposure instead of up to 10 serialized round-trips.
  uint4 rk[FPT];
#pragma unroll
  for (int i = 0; i < FPT; ++i) rk[i] = packed[tid + i * TPB];

  f4 x4[FPT];
#pragma unroll
  for (int i = 0; i < FPT; ++i) {
    uint4 r = rk[i];
    f4 s = in4[r.x & 0xFFFFu];          // ds_read_b128: 4 rows per gather
    s += in4[r.x >> 16];
    s += in4[r.y & 0xFFFFu];
    s += in4[r.y >> 16];
    s += in4[r.z & 0xFFFFu];
    s += in4[r.z >> 16];
    x4[i] = s;
#pragma unroll
    for (int rr = 0; rr < ROWS; ++rr) {
      float v = s[rr];
      if (v >= 4.0f) {                  // top-32 of 10240 ~ 4.8; bin >=4 only
        int b = (int)((v - 4.0f) * 512.0f);    // EXACT key (Sterbenz + pow2)
        b = b > NBINS - 1 ? NBINS - 1 : b;
        atomicAdd(&hist[rr * NBINS + b], 1);
      }
    }
  }
  __syncthreads();

  // --- phase 2: wave-parallel bracket-bin search (wave r owns row r) -----
  // Lane L sums bins [16L, 16L+16); 6-step shfl suffix scan; crossing lane
  // walks its 16 bins descending to the exact bin. No internal barriers.
  if (wid < ROWS) {
    const int r = wid;
    const int base = r * NBINS + lane * 16;
    int csum = 0;
#pragma unroll
    for (int j = 0; j < 16; ++j) csum += hist[base + j];
    int s = csum;                       // inclusive suffix sum across lanes
#pragma unroll
    for (int off = 1; off < 64; off <<= 1) {
      int t = __shfl_down(s, off);
      if (lane + off < 64) s += t;
    }
    int s_next = __shfl_down(s, 1);     // suffix starting at lane+1
    if (lane == 63) s_next = 0;
    if (s >= k && s_next < k) {         // unique crossing chunk (if any)
      int acc = s_next;
      int bsel = lane * 16, abv = s_next;
      for (int b = lane * 16 + 15; b >= lane * 16; --b) {
        int h = hist[r * NBINS + b];
        if (acc + h >= k) { bsel = b; abv = acc; break; }
        acc += h;
      }
      sh_bstar[r] = bsel;
      sh_above[r] = abv;
      sh_n[r]     = hist[r * NBINS + bsel];
    }
  }
  __syncthreads();

  // --- phase 3a: collect bracket-bin members into per-row lists ----------
  {
    const int b0 = sh_bstar[0], b1 = sh_bstar[1];
    const int b2 = sh_bstar[2], b3 = sh_bstar[3];
#pragma unroll
    for (int i = 0; i < FPT; ++i) {
      f4 s = x4[i];
#pragma unroll
      for (int rr = 0; rr < ROWS; ++rr) {
        float v = s[rr];
        int bb = (rr == 0) ? b0 : (rr == 1) ? b1 : (rr == 2) ? b2 : b3;
        if (v >= 4.0f) {
          int b = (int)((v - 4.0f) * 512.0f);
          b = b > NBINS - 1 ? NBINS - 1 : b;
          if (b == bb) {
            int p = atomicAdd(&sh_cnt[rr], 1);
            if (p < CAP) sh_list[rr][p] = v;
          }
        }
      }
    }
  }
  __syncthreads();

  // --- phase 3b: wave r rank-selects the (k-above)-th largest in its list -
  if (wid < ROWS) {
    const int r   = wid;
    const int bst = sh_bstar[r];
    const int n   = (bst >= 0) ? sh_n[r] : CAP + 1;
    if (bst >= 0 && n <= CAP && sh_cnt[r] <= CAP) {
      const int j = k - sh_above[r];            // 1 <= j <= n
      float vl = (lane < n) ? sh_list[r][lane] : -1.0f;
      int cgt = 0, cge = 0;
      for (int m = 0; m < n; ++m) {
        float u = sh_list[r][m];                // broadcast LDS read
        cgt += (u > vl);
        cge += (u >= vl);
      }
      if (lane < n && cgt < j && cge >= j) sh_thr[r] = vl;  // exact k-th bits
      if (lane == 0) sh_need[r] = 0;
    } else {
      if (lane == 0) sh_need[r] = 1;            // overflow / no bracket
    }
  }
  __syncthreads();

  // --- phase 4: fallback (recomputes from LDS, never touches x4; rare) ---
#pragma unroll 1
  for (int r = 0; r < ROWS; ++r) {
    if (!sh_need[r]) continue;
    unsigned lo = 0u, hi = __float_as_uint(8.0f);
    while (lo < hi) {
      unsigned mid = lo + ((hi - lo + 1u) >> 1);
      float fm = __uint_as_float(mid);
      int c = 0;
      for (int i = 0; i < FPT; ++i) {
        uint4 p = packed[tid + i * TPB];
        c += (int)__popcll(__ballot(row_val(in4, p, r) >= fm));
      }
      if (lane == 0) wsum[wid] = c;
      __syncthreads();
      int tot = 0;
#pragma unroll
      for (int w = 0; w < NWAVES; ++w) tot += wsum[w];
      if (tot >= k) lo = mid; else hi = mid - 1u;
      __syncthreads();
    }
    if (tid == 0) sh_thr[r] = __uint_as_float(lo);
    __syncthreads();
  }
  const float t0 = sh_thr[0];
  const float t1 = sh_thr[1];
  const float t2 = sh_thr[2];
  const float t3 = sh_thr[3];

  // --- phase 5: thresholded writes, 4 coalesced nontemporal streams ------
  float* o0 = out + (size_t)(row0 + 0) * OUT_F;
  float* o1 = out + (size_t)(row0 + 1) * OUT_F;
  float* o2 = out + (size_t)(row0 + 2) * OUT_F;
  float* o3 = out + (size_t)(row0 + 3) * OUT_F;
#pragma unroll
  for (int i = 0; i < FPT; ++i) {
    int f = tid + i * TPB;
    f4 v = x4[i];
    __builtin_nontemporal_store((v.x >= t0) ? v.x : 0.0f, &o0[f]);
    __builtin_nontemporal_store((v.y >= t1) ? v.y : 0.0f, &o1[f]);
    __builtin_nontemporal_store((v.z >= t2) ? v.z : 0.0f, &o2[f]);
    __builtin_nontemporal_store((v.w >= t3) ? v.w : 0.0f, &o3[f]);
  }
}

// ---------------------------------------------------------------------------
extern "C" void kernel_launch(void* const* d_in, const int* in_sizes, int n_in,
                              void* d_out, int out_size, void* d_ws, size_t ws_size,
                              hipStream_t stream) {
  const float* inp = (const float*)d_in[0];
  const float* W   = (const float*)d_in[1];
  const int* kptr  = (const int*)d_in[2];
  float* out       = (float*)d_out;

  const int batch = in_sizes[0] / IN_F;   // 4096
  const int out_f = in_sizes[1] / IN_F;   // 10240

  uint4* packed = (uint4*)d_ws;           // 10240 * 16 B = 160 KB scratch

  hipLaunchKernelGGL(extract_idx, dim3((out_f + 3) / 4), dim3(256), 0, stream,
                     W, packed, out_f);
  hipLaunchKernelGGL(fly_hash, dim3(batch / ROWS), dim3(TPB), 0, stream,
                     inp, packed, kptr, out);
}